// Round 7
// baseline (1181.092 us; speedup 1.0000x reference)
//
#include <hip/hip_runtime.h>
#include <hip/hip_bf16.h>

#define T_LEN 2048
#define B_SZ  64
#define D_IN  64
#define H_SZ  128

// ---------------------------------------------------------------------------
// Kernel 1: collapse fc1+fc2 (no nonlinearity between them) into
//   w_eff[i] = sum_o fc2_W[o] * fc1_W[o, i]   (i in [0,256))
//   b_eff    = sum_o fc2_W[o] * fc1_b[o] + fc2_b
// ws layout (floats): [0..255]=w_eff, [256]=b_eff, [512..]=partials, then xp
// ---------------------------------------------------------------------------
__global__ __launch_bounds__(256)
void prep_kernel(const float* __restrict__ fc1_W, const float* __restrict__ fc1_b,
                 const float* __restrict__ fc2_W, const float* __restrict__ fc2_b,
                 float* __restrict__ ws)
{
    const int i = threadIdx.x;  // 0..255
    float s = 0.0f;
    #pragma unroll 4
    for (int o = 0; o < 128; ++o) s = fmaf(fc2_W[o], fc1_W[o * 256 + i], s);
    ws[i] = s;

    __shared__ float red[128];
    if (i < 128) red[i] = fc2_W[i] * fc1_b[i];
    __syncthreads();
    if (i == 0) {
        float b = fc2_b[0];
        for (int o = 0; o < 128; ++o) b += red[o];
        ws[256] = b;
    }
}

// ---------------------------------------------------------------------------
// Kernel 1b (v3): xp[(dir*64+b)][t][j] = x[b,t,:]·Wih[j,:] + bih[j] + bhh[j]
// LDS-staged x ([64 t][68 pad]) and Wih ([128 j][68 pad]); thread tile
// 8 j x 4 t with stride-16 lane interleave (j = jg+16*jj, t = tg+16*tt) so
// every b128 LDS read is 2-way-at-worst on banks (free). All operand reads
// are b128; no per-iteration global/scalar refetch (the v2 mistake).
// Grid: 4096 = dir(2) x b(64) x tc(32 chunks of 64 t); 256 threads.
// ---------------------------------------------------------------------------
__global__ __launch_bounds__(256, 2)
void xp_gemm(const float* __restrict__ x,
             const float* __restrict__ Wih_f, const float* __restrict__ bih_f,
             const float* __restrict__ bhh_f,
             const float* __restrict__ Wih_b, const float* __restrict__ bih_b,
             const float* __restrict__ bhh_b,
             float* __restrict__ xp)
{
    const int blk = blockIdx.x;
    const int dir = blk >> 11;
    const int b   = (blk >> 5) & 63;
    const int tc  = blk & 31;
    const int tid = threadIdx.x;

    const float* __restrict__ Wih = dir ? Wih_b : Wih_f;
    const float* __restrict__ bih = dir ? bih_b : bih_f;
    const float* __restrict__ bhh = dir ? bhh_b : bhh_f;

    __shared__ __align__(16) float xs[64][68];    // 17.4 KB
    __shared__ __align__(16) float wsd[128][68];  // 34.8 KB
    __shared__ float bs[128];

    {   // stage x chunk (64 t x 64 d) and Wih (128 j x 64 d)
        const float4* src = (const float4*)(x + ((size_t)b * T_LEN + tc * 64) * D_IN);
        #pragma unroll
        for (int r = 0; r < 4; ++r) {
            int q = tid + 256 * r;          // f4 idx: t = q>>4, d0 = (q&15)*4
            float4 v = src[q];
            *(float4*)&xs[q >> 4][(q & 15) * 4] = v;
        }
        const float4* wsrc = (const float4*)Wih;
        #pragma unroll
        for (int r = 0; r < 8; ++r) {
            int q = tid + 256 * r;          // f4 idx: j = q>>4, k0 = (q&15)*4
            float4 v = wsrc[q];
            *(float4*)&wsd[q >> 4][(q & 15) * 4] = v;
        }
        if (tid < 128) bs[tid] = bih[tid] + bhh[tid];
    }
    __syncthreads();

    const int jg = tid & 15;   // j = jg + 16*jj
    const int tg = tid >> 4;   // t = tg + 16*tt

    float acc[8][4];
    #pragma unroll
    for (int jj = 0; jj < 8; ++jj)
        #pragma unroll
        for (int tt = 0; tt < 4; ++tt) acc[jj][tt] = 0.0f;

    #pragma unroll 2
    for (int kc = 0; kc < 16; ++kc) {
        float4 xv[4];
        #pragma unroll
        for (int tt = 0; tt < 4; ++tt)
            xv[tt] = *(const float4*)&xs[tg + 16 * tt][kc * 4];
        #pragma unroll
        for (int jj = 0; jj < 8; ++jj) {
            float4 wv = *(const float4*)&wsd[jg + 16 * jj][kc * 4];
            #pragma unroll
            for (int tt = 0; tt < 4; ++tt) {
                acc[jj][tt] = fmaf(wv.x, xv[tt].x, acc[jj][tt]);
                acc[jj][tt] = fmaf(wv.y, xv[tt].y, acc[jj][tt]);
                acc[jj][tt] = fmaf(wv.z, xv[tt].z, acc[jj][tt]);
                acc[jj][tt] = fmaf(wv.w, xv[tt].w, acc[jj][tt]);
            }
        }
    }

    float* xpo = xp + ((size_t)(dir * 64 + b) * T_LEN + tc * 64) * H_SZ;
    #pragma unroll
    for (int jj = 0; jj < 8; ++jj) {
        const float bj = bs[jg + 16 * jj];
        #pragma unroll
        for (int tt = 0; tt < 4; ++tt)
            xpo[(size_t)(tg + 16 * tt) * H_SZ + jg + 16 * jj] = acc[jj][tt] + bj;
    }
}

// DPP add: v += dpp_moved(v); bound_ctrl=true -> invalid source lanes give 0.
#define DPP_ADD_F32(v, ctrl)                                                   \
    v += __int_as_float(__builtin_amdgcn_update_dpp(                           \
            0, __float_as_int(v), (ctrl), 0xf, 0xf, true))

// Relaxed barrier: lgkmcnt(0) (ds visibility) without the vmcnt(0) drain.
__device__ __forceinline__ void chain_barrier() {
    asm volatile("s_waitcnt lgkmcnt(0)" ::: "memory");
    __builtin_amdgcn_s_barrier();
    asm volatile("" ::: "memory");
}
// Strict variant for the fallback kernel.
__device__ __forceinline__ void chain_barrier_strict() {
    asm volatile("s_waitcnt lgkmcnt(0)" ::: "memory");
    __builtin_amdgcn_s_barrier();
    __builtin_amdgcn_sched_barrier(0);
}

// h LDS layout: float k stored at index k + 4*(k>>4)  (80B row stride).
// Group g (k = g*16..+15) = 16 contiguous floats at index 20*g -> bank
// starts {0,20,8,28,16,4,24,12} -> conflict-free b128 reads.

// One chain-step: read h, 64 FMA, k-group DPP reduce, relu, h write,
// logit partial dot + wave DPP reduce, lane-63 store. XC is consumed then
// refilled with the prefetch for step s+2.
__device__ __forceinline__
void chain_step(const float* __restrict__ wh, float4& XC,
                const float4* __restrict__ rdp, float* __restrict__ wrp,
                const float4 w4, float* __restrict__ po, int tt,
                const float* __restrict__ pref, int g, bool wr, int l)
{
    float4 hv[4];
    #pragma unroll
    for (int i = 0; i < 4; ++i) hv[i] = rdp[i];

    float a0 = (g == 0) ? XC.x : 0.0f;
    float a1 = (g == 0) ? XC.y : 0.0f;
    float a2 = (g == 0) ? XC.z : 0.0f;
    float a3 = (g == 0) ? XC.w : 0.0f;
    XC = *(const float4*)pref;   // prefetch (distance 2)

    #pragma unroll
    for (int i = 0; i < 4; ++i) {
        #pragma unroll
        for (int c = 0; c < 4; ++c) {
            const float h_ = ((const float*)&hv[i])[c];
            a0 = fmaf(wh[ 0 + i * 4 + c], h_, a0);
            a1 = fmaf(wh[16 + i * 4 + c], h_, a1);
            a2 = fmaf(wh[32 + i * 4 + c], h_, a2);
            a3 = fmaf(wh[48 + i * 4 + c], h_, a3);
        }
    }
    DPP_ADD_F32(a0, 0x111); DPP_ADD_F32(a1, 0x111);
    DPP_ADD_F32(a2, 0x111); DPP_ADD_F32(a3, 0x111);
    DPP_ADD_F32(a0, 0x112); DPP_ADD_F32(a1, 0x112);
    DPP_ADD_F32(a2, 0x112); DPP_ADD_F32(a3, 0x112);
    DPP_ADD_F32(a0, 0x114); DPP_ADD_F32(a1, 0x114);
    DPP_ADD_F32(a2, 0x114); DPP_ADD_F32(a3, 0x114);

    float4 h4;
    h4.x = fmaxf(a0, 0.0f); h4.y = fmaxf(a1, 0.0f);
    h4.z = fmaxf(a2, 0.0f); h4.w = fmaxf(a3, 0.0f);

    float pv = 0.0f;
    if (wr) {
        *(float4*)wrp = h4;
        pv = fmaf(w4.x, h4.x, fmaf(w4.y, h4.y, fmaf(w4.z, h4.z, w4.w * h4.w)));
    }
    DPP_ADD_F32(pv, 0x118);  // row_shr:8
    DPP_ADD_F32(pv, 0x142);  // row_bcast:15
    DPP_ADD_F32(pv, 0x143);  // row_bcast:31
    if (l == 63) po[tt] = pv;
}

// ---------------------------------------------------------------------------
// Kernel 2 (dual-chain): one block per BATCH handles BOTH directions.
// 64 blocks x 256 threads, 1 wave/SIMD. Per barrier period each wave steps
// chain-F then chain-B: the two chains' ds_reads/FMAs interleave into the
// same latency shadow and the barrier+lgkm cost is paid once per 2 steps.
// ---------------------------------------------------------------------------
__global__ __launch_bounds__(256, 1)
void brnn_recur_dual(const float* __restrict__ xp,
                     const float* __restrict__ Whh_f, const float* __restrict__ Whh_b,
                     const float* __restrict__ weff,  float* __restrict__ partbuf)
{
    const int b   = blockIdx.x;   // 0..63
    const int tid = threadIdx.x;
    const int w   = tid >> 6;
    const int l   = tid & 63;
    const int g   = l & 7;
    const int m   = l >> 3;
    const int j0  = w * 32 + m * 4;
    const bool wr = (g == 7);

    float whF[64], whB[64];
    #pragma unroll
    for (int jj = 0; jj < 4; ++jj)
        #pragma unroll
        for (int i = 0; i < 4; ++i) {
            ((float4*)whF)[jj * 4 + i] =
                *(const float4*)(Whh_f + (j0 + jj) * H_SZ + g * 16 + i * 4);
            ((float4*)whB)[jj * 4 + i] =
                *(const float4*)(Whh_b + (j0 + jj) * H_SZ + g * 16 + i * 4);
        }

    const float4 w4F = *(const float4*)(weff + j0);
    const float4 w4B = *(const float4*)(weff + H_SZ + j0);

    __shared__ __align__(16) float hF[2][160], hB[2][160];
    if (tid < 160) { hF[0][tid] = 0.0f; hB[0][tid] = 0.0f; }
    __syncthreads();

    const float* xpF = xp + (size_t)b * T_LEN * H_SZ + j0;
    const float* xpB = xp + (size_t)(64 + b) * T_LEN * H_SZ + j0;
    float* poF = partbuf + ((size_t)b * 4 + w) * T_LEN;
    float* poB = partbuf + ((size_t)(64 + b) * 4 + w) * T_LEN;

    const float4* rF0 = (const float4*)&hF[0][20 * g];
    const float4* rF1 = (const float4*)&hF[1][20 * g];
    const float4* rB0 = (const float4*)&hB[0][20 * g];
    const float4* rB1 = (const float4*)&hB[1][20 * g];
    const int hwidx = 40 * w + 4 * m + 4 * (m >> 2);
    float* wF0 = &hF[0][hwidx];
    float* wF1 = &hF[1][hwidx];
    float* wB0 = &hB[0][hwidx];
    float* wB1 = &hB[1][hwidx];

    float4 xF0 = *(const float4*)(xpF);
    float4 xF1 = *(const float4*)(xpF + (size_t)1 * H_SZ);
    float4 xB0 = *(const float4*)(xpB + (size_t)(T_LEN - 1) * H_SZ);
    float4 xB1 = *(const float4*)(xpB + (size_t)(T_LEN - 2) * H_SZ);

    #pragma unroll 1
    for (int s = 0; s < T_LEN; s += 2) {
        {   // even step: read par 0, write par 1
            const int spF = (s + 2 < T_LEN) ? s + 2 : T_LEN - 1;
            const int spB = (s + 2 < T_LEN) ? (T_LEN - 3 - s) : 0;
            chain_step(whF, xF0, rF0, wF1, w4F, poF, s,
                       xpF + (size_t)spF * H_SZ, g, wr, l);
            chain_step(whB, xB0, rB0, wB1, w4B, poB, T_LEN - 1 - s,
                       xpB + (size_t)spB * H_SZ, g, wr, l);
            chain_barrier();
        }
        {   // odd step: read par 1, write par 0
            const int sq  = s + 1;
            const int sqF = (sq + 2 < T_LEN) ? sq + 2 : T_LEN - 1;
            const int sqB = (sq + 2 < T_LEN) ? (T_LEN - 3 - sq) : 0;
            chain_step(whF, xF1, rF1, wF0, w4F, poF, sq,
                       xpF + (size_t)sqF * H_SZ, g, wr, l);
            chain_step(whB, xB1, rB1, wB0, w4B, poB, T_LEN - 1 - sq,
                       xpB + (size_t)sqB * H_SZ, g, wr, l);
            chain_barrier();
        }
    }
}

// ---------------------------------------------------------------------------
// Fallback recurrence (round-4 structure, x in-loop) for small ws_size.
// ---------------------------------------------------------------------------
__global__ __launch_bounds__(256, 1)
void brnn_recur_fb(const float* __restrict__ x,
                   const float* __restrict__ Wih_f, const float* __restrict__ Whh_f,
                   const float* __restrict__ bih_f, const float* __restrict__ bhh_f,
                   const float* __restrict__ Wih_b, const float* __restrict__ Whh_b,
                   const float* __restrict__ bih_b, const float* __restrict__ bhh_b,
                   const float* __restrict__ weff,  float* __restrict__ partbuf)
{
    const int blk  = blockIdx.x;
    const int dir  = blk >> 6;
    const int b    = blk & 63;
    const int tid  = threadIdx.x;
    const int w    = tid >> 6;
    const int l    = tid & 63;
    const int g    = l & 7;
    const int m    = l >> 3;
    const int j0   = w * 32 + m * 4;
    const bool wr  = (g == 7);

    const float* Wih = dir ? Wih_b : Wih_f;
    const float* Whh = dir ? Whh_b : Whh_f;
    const float* bih = dir ? bih_b : bih_f;
    const float* bhh = dir ? bhh_b : bhh_f;

    float whh[64];
    #pragma unroll
    for (int jj = 0; jj < 4; ++jj)
        #pragma unroll
        for (int i = 0; i < 4; ++i)
            ((float4*)whh)[jj * 4 + i] =
                *(const float4*)(Whh + (j0 + jj) * 128 + g * 16 + i * 4);
    float wih[32];
    #pragma unroll
    for (int jj = 0; jj < 4; ++jj)
        #pragma unroll
        for (int i = 0; i < 2; ++i)
            ((float4*)wih)[jj * 2 + i] =
                *(const float4*)(Wih + (j0 + jj) * 64 + g * 8 + i * 4);

    float4 b4 = make_float4(0.f, 0.f, 0.f, 0.f);
    if (g == 0) {
        float4 bi = *(const float4*)(bih + j0);
        float4 bh = *(const float4*)(bhh + j0);
        b4 = make_float4(bi.x + bh.x, bi.y + bh.y, bi.z + bh.z, bi.w + bh.w);
    }
    const float4 w4 = *(const float4*)(weff + dir * 128 + j0);

    __shared__ __align__(16) float hbuf[2][160];
    if (tid < 160) hbuf[0][tid] = 0.0f;
    __syncthreads();

    const float* xbase = x + (size_t)b * T_LEN * D_IN + g * 8;
    float* pout = partbuf + ((size_t)blk * 4 + w) * T_LEN;

    float xq0[8], xq1[8], xq2[8], xq3[8];
    {
        const float4* xp0 = (const float4*)(xbase + (size_t)(dir ? (T_LEN - 1) : 0) * D_IN);
        ((float4*)xq0)[0] = xp0[0];
        ((float4*)xq0)[1] = xp0[1];
        const float4* xp1 = (const float4*)(xbase + (size_t)(dir ? (T_LEN - 2) : 1) * D_IN);
        ((float4*)xq1)[0] = xp1[0];
        ((float4*)xq1)[1] = xp1[1];
    }

    float p_carry = 0.0f;
    int   t_prev  = 0;
    const int hwidx = 40 * w + 4 * m + 4 * (m >> 2);

#define STEP(S, RD, XCUR, XPRE) do {                                           \
        const int s_  = (S);                                                   \
        if (s_ > 0) {                                                          \
            float pr_ = p_carry;                                               \
            DPP_ADD_F32(pr_, 0x118); DPP_ADD_F32(pr_, 0x142);                  \
            DPP_ADD_F32(pr_, 0x143);                                           \
            if (l == 63) pout[t_prev] = pr_;                                   \
        }                                                                      \
        {                                                                      \
            const int sp_ = (s_ + 2 < T_LEN) ? (s_ + 2) : (T_LEN - 1);         \
            const int tp_ = dir ? (T_LEN - 1 - sp_) : sp_;                     \
            const float4* xp_ = (const float4*)(xbase + (size_t)tp_ * D_IN);   \
            ((float4*)XPRE)[0] = xp_[0];                                       \
            ((float4*)XPRE)[1] = xp_[1];                                       \
        }                                                                      \
        const float4* hp_ = (const float4*)&hbuf[RD][20 * g];                  \
        float4 hv_[4];                                                         \
        _Pragma("unroll") for (int i = 0; i < 4; ++i) hv_[i] = hp_[i];         \
        float a0 = b4.x, a1 = b4.y, a2 = b4.z, a3 = b4.w;                      \
        _Pragma("unroll") for (int i = 0; i < 8; ++i) {                        \
            a0 = fmaf(wih[0 * 8 + i], XCUR[i], a0);                            \
            a1 = fmaf(wih[1 * 8 + i], XCUR[i], a1);                            \
            a2 = fmaf(wih[2 * 8 + i], XCUR[i], a2);                            \
            a3 = fmaf(wih[3 * 8 + i], XCUR[i], a3);                            \
        }                                                                      \
        _Pragma("unroll") for (int i = 0; i < 4; ++i) {                        \
            const float* hq_ = (const float*)&hv_[i];                          \
            _Pragma("unroll") for (int c = 0; c < 4; ++c) {                    \
                a0 = fmaf(whh[0 * 16 + i * 4 + c], hq_[c], a0);                \
                a1 = fmaf(whh[1 * 16 + i * 4 + c], hq_[c], a1);                \
                a2 = fmaf(whh[2 * 16 + i * 4 + c], hq_[c], a2);                \
                a3 = fmaf(whh[3 * 16 + i * 4 + c], hq_[c], a3);                \
            }                                                                  \
        }                                                                      \
        DPP_ADD_F32(a0, 0x111); DPP_ADD_F32(a1, 0x111);                        \
        DPP_ADD_F32(a2, 0x111); DPP_ADD_F32(a3, 0x111);                        \
        DPP_ADD_F32(a0, 0x112); DPP_ADD_F32(a1, 0x112);                        \
        DPP_ADD_F32(a2, 0x112); DPP_ADD_F32(a3, 0x112);                        \
        DPP_ADD_F32(a0, 0x114); DPP_ADD_F32(a1, 0x114);                        \
        DPP_ADD_F32(a2, 0x114); DPP_ADD_F32(a3, 0x114);                        \
        float4 h4_;                                                            \
        h4_.x = fmaxf(a0, 0.0f); h4_.y = fmaxf(a1, 0.0f);                      \
        h4_.z = fmaxf(a2, 0.0f); h4_.w = fmaxf(a3, 0.0f);                      \
        p_carry = 0.0f;                                                        \
        if (wr) {                                                              \
            *(float4*)&hbuf[(RD) ^ 1][hwidx] = h4_;                            \
            p_carry = w4.x * h4_.x + w4.y * h4_.y                              \
                    + w4.z * h4_.z + w4.w * h4_.w;                             \
        }                                                                      \
        t_prev = dir ? (T_LEN - 1 - s_) : s_;                                  \
        chain_barrier_strict();                                                \
    } while (0)

    #pragma unroll 1
    for (int s = 0; s < T_LEN; s += 4) {
        STEP(s,     0, xq0, xq2);
        STEP(s + 1, 1, xq1, xq3);
        STEP(s + 2, 0, xq2, xq0);
        STEP(s + 3, 1, xq3, xq1);
    }
#undef STEP

    {
        float pr = p_carry;
        DPP_ADD_F32(pr, 0x118); DPP_ADD_F32(pr, 0x142); DPP_ADD_F32(pr, 0x143);
        if (l == 63) pout[t_prev] = pr;
    }
}

// ---------------------------------------------------------------------------
// Kernel 3: assemble logits from partials and log-softmax over T per batch.
// ---------------------------------------------------------------------------
__global__ __launch_bounds__(256)
void brnn_lsm(const float* __restrict__ partbuf, const float* __restrict__ ws,
              float* __restrict__ out)
{
    const int b   = blockIdx.x;
    const int tid = threadIdx.x;
    __shared__ float lg[T_LEN];
    __shared__ float red[8];

    const float beff = ws[256];

    float lmax = -3.0e38f;
    for (int t = tid; t < T_LEN; t += 256) {
        float s = beff;
        #pragma unroll
        for (int dw = 0; dw < 8; ++dw) {
            const int dir = dw >> 2, wv = dw & 3;
            s += partbuf[(((size_t)(dir * 64 + b)) * 4 + wv) * T_LEN + t];
        }
        lg[t] = s;
        lmax = fmaxf(lmax, s);
    }
    #pragma unroll
    for (int mm = 1; mm <= 32; mm <<= 1) lmax = fmaxf(lmax, __shfl_xor(lmax, mm));
    if ((tid & 63) == 0) red[tid >> 6] = lmax;
    __syncthreads();
    const float bmax = fmaxf(fmaxf(red[0], red[1]), fmaxf(red[2], red[3]));

    float lsum = 0.0f;
    for (int t = tid; t < T_LEN; t += 256) lsum += expf(lg[t] - bmax);
    #pragma unroll
    for (int mm = 1; mm <= 32; mm <<= 1) lsum += __shfl_xor(lsum, mm);
    if ((tid & 63) == 0) red[4 + (tid >> 6)] = lsum;
    __syncthreads();
    const float lse = bmax + logf(red[4] + red[5] + red[6] + red[7]);

    for (int t = tid; t < T_LEN; t += 256)
        out[(size_t)b * T_LEN + t] = lg[t] - lse;
}

// ---------------------------------------------------------------------------
extern "C" void kernel_launch(void* const* d_in, const int* in_sizes, int n_in,
                              void* d_out, int out_size, void* d_ws, size_t ws_size,
                              hipStream_t stream)
{
    const float* x     = (const float*)d_in[0];
    const float* Wih_f = (const float*)d_in[1];
    const float* Whh_f = (const float*)d_in[2];
    const float* bih_f = (const float*)d_in[3];
    const float* bhh_f = (const float*)d_in[4];
    const float* Wih_b = (const float*)d_in[5];
    const float* Whh_b = (const float*)d_in[6];
    const float* bih_b = (const float*)d_in[7];
    const float* bhh_b = (const float*)d_in[8];
    const float* fc1_W = (const float*)d_in[9];
    const float* fc1_b = (const float*)d_in[10];
    const float* fc2_W = (const float*)d_in[11];
    const float* fc2_b = (const float*)d_in[12];
    float* out = (float*)d_out;

    float* wsf = (float*)d_ws;
    const size_t part_off   = 512;
    const size_t part_elems = (size_t)2 * 64 * 4 * T_LEN;          // 1 Mi floats
    const size_t xp_off     = part_off + part_elems;
    const size_t xp_elems   = (size_t)2 * 64 * T_LEN * H_SZ;       // 32 Mi floats
    float* part = wsf + part_off;
    float* xpbf = wsf + xp_off;
    const bool big_ws = ws_size >= (xp_off + xp_elems) * sizeof(float);

    hipLaunchKernelGGL(prep_kernel, dim3(1), dim3(256), 0, stream,
                       fc1_W, fc1_b, fc2_W, fc2_b, wsf);
    if (big_ws) {
        hipLaunchKernelGGL(xp_gemm, dim3(4096), dim3(256), 0, stream,
                           x, Wih_f, bih_f, bhh_f, Wih_b, bih_b, bhh_b, xpbf);
        hipLaunchKernelGGL(brnn_recur_dual, dim3(64), dim3(256), 0, stream,
                           xpbf, Whh_f, Whh_b, wsf, part);
    } else {
        hipLaunchKernelGGL(brnn_recur_fb, dim3(128), dim3(256), 0, stream,
                           x, Wih_f, Whh_f, bih_f, bhh_f,
                           Wih_b, Whh_b, bih_b, bhh_b, wsf, part);
    }
    hipLaunchKernelGGL(brnn_lsm, dim3(64), dim3(256), 0, stream,
                       part, wsf, out);
}

// Round 8
// 871.343 us; speedup vs baseline: 1.3555x; 1.3555x over previous
//
#include <hip/hip_runtime.h>
#include <hip/hip_bf16.h>

#define T_LEN 2048
#define B_SZ  64
#define D_IN  64
#define H_SZ  128

// ---------------------------------------------------------------------------
// Kernel 1: collapse fc1+fc2 into w_eff[256], b_eff.
// ws layout (floats): [0..255]=w_eff, [256]=b_eff, [512..]=partials, then xp
// ---------------------------------------------------------------------------
__global__ __launch_bounds__(256)
void prep_kernel(const float* __restrict__ fc1_W, const float* __restrict__ fc1_b,
                 const float* __restrict__ fc2_W, const float* __restrict__ fc2_b,
                 float* __restrict__ ws)
{
    const int i = threadIdx.x;  // 0..255
    float s = 0.0f;
    #pragma unroll 4
    for (int o = 0; o < 128; ++o) s = fmaf(fc2_W[o], fc1_W[o * 256 + i], s);
    ws[i] = s;

    __shared__ float red[128];
    if (i < 128) red[i] = fc2_W[i] * fc1_b[i];
    __syncthreads();
    if (i == 0) {
        float b = fc2_b[0];
        for (int o = 0; o < 128; ++o) b += red[o];
        ws[256] = b;
    }
}

// ---------------------------------------------------------------------------
// Kernel 1b (v3, proven r7): xp[(dir*64+b)][t][j] = x·Wih^T + bih + bhh.
// LDS-staged x and Wih, 8jx4t thread tile, stride-16 interleave.
// ---------------------------------------------------------------------------
__global__ __launch_bounds__(256, 2)
void xp_gemm(const float* __restrict__ x,
             const float* __restrict__ Wih_f, const float* __restrict__ bih_f,
             const float* __restrict__ bhh_f,
             const float* __restrict__ Wih_b, const float* __restrict__ bih_b,
             const float* __restrict__ bhh_b,
             float* __restrict__ xp)
{
    const int blk = blockIdx.x;
    const int dir = blk >> 11;
    const int b   = (blk >> 5) & 63;
    const int tc  = blk & 31;
    const int tid = threadIdx.x;

    const float* __restrict__ Wih = dir ? Wih_b : Wih_f;
    const float* __restrict__ bih = dir ? bih_b : bih_f;
    const float* __restrict__ bhh = dir ? bhh_b : bhh_f;

    __shared__ __align__(16) float xs[64][68];
    __shared__ __align__(16) float wsd[128][68];
    __shared__ float bs[128];

    {
        const float4* src = (const float4*)(x + ((size_t)b * T_LEN + tc * 64) * D_IN);
        #pragma unroll
        for (int r = 0; r < 4; ++r) {
            int q = tid + 256 * r;
            float4 v = src[q];
            *(float4*)&xs[q >> 4][(q & 15) * 4] = v;
        }
        const float4* wsrc = (const float4*)Wih;
        #pragma unroll
        for (int r = 0; r < 8; ++r) {
            int q = tid + 256 * r;
            float4 v = wsrc[q];
            *(float4*)&wsd[q >> 4][(q & 15) * 4] = v;
        }
        if (tid < 128) bs[tid] = bih[tid] + bhh[tid];
    }
    __syncthreads();

    const int jg = tid & 15;
    const int tg = tid >> 4;

    float acc[8][4];
    #pragma unroll
    for (int jj = 0; jj < 8; ++jj)
        #pragma unroll
        for (int tt = 0; tt < 4; ++tt) acc[jj][tt] = 0.0f;

    #pragma unroll 2
    for (int kc = 0; kc < 16; ++kc) {
        float4 xv[4];
        #pragma unroll
        for (int tt = 0; tt < 4; ++tt)
            xv[tt] = *(const float4*)&xs[tg + 16 * tt][kc * 4];
        #pragma unroll
        for (int jj = 0; jj < 8; ++jj) {
            float4 wv = *(const float4*)&wsd[jg + 16 * jj][kc * 4];
            #pragma unroll
            for (int tt = 0; tt < 4; ++tt) {
                acc[jj][tt] = fmaf(wv.x, xv[tt].x, acc[jj][tt]);
                acc[jj][tt] = fmaf(wv.y, xv[tt].y, acc[jj][tt]);
                acc[jj][tt] = fmaf(wv.z, xv[tt].z, acc[jj][tt]);
                acc[jj][tt] = fmaf(wv.w, xv[tt].w, acc[jj][tt]);
            }
        }
    }

    float* xpo = xp + ((size_t)(dir * 64 + b) * T_LEN + tc * 64) * H_SZ;
    #pragma unroll
    for (int jj = 0; jj < 8; ++jj) {
        const float bj = bs[jg + 16 * jj];
        #pragma unroll
        for (int tt = 0; tt < 4; ++tt)
            xpo[(size_t)(tg + 16 * tt) * H_SZ + jg + 16 * jj] = acc[jj][tt] + bj;
    }
}

// DPP add: v += dpp_moved(v); bound_ctrl=true -> invalid source lanes give 0.
#define DPP_ADD_F32(v, ctrl)                                                   \
    v += __int_as_float(__builtin_amdgcn_update_dpp(                           \
            0, __float_as_int(v), (ctrl), 0xf, 0xf, true))

// Relaxed barrier: lgkmcnt(0) (ds visibility) without the vmcnt(0) drain.
__device__ __forceinline__ void chain_barrier() {
    asm volatile("s_waitcnt lgkmcnt(0)" ::: "memory");
    __builtin_amdgcn_s_barrier();
    asm volatile("" ::: "memory");
}
// Strict variant for the fallback kernel.
__device__ __forceinline__ void chain_barrier_strict() {
    asm volatile("s_waitcnt lgkmcnt(0)" ::: "memory");
    __builtin_amdgcn_s_barrier();
    __builtin_amdgcn_sched_barrier(0);
}

// h LDS layout (J8K8): float k at idx k + 4*(k>>3)  (48B group stride).
// Group g (k = 8g..8g+7) = 8 contiguous floats at idx 12g; bank start
// 12g mod 32 covers {0,12,24,4,16,28,8,20} twice -> worst 2-way (free).

// ---------------------------------------------------------------------------
// Kernel 2 (J8K8): one block per (dir,batch) chain, 256 threads, 1 wave/SIMD.
// Lane (w, l): g = l&15 -> k-slice [8g,8g+8); m = l>>4 -> 8 outputs
// j0 = w*32 + m*8. Step: 2 ds_read_b128 -> 64 FMA (8 accs) -> 4-level DPP
// k-reduce (lane 15 of each row) -> writer adds xp, relu, 2 ds_write_b128,
// 8-wide w_eff dot -> 2-level DPP p-reduce -> burst p-store per 8 steps.
// ---------------------------------------------------------------------------
template<int DIR>
__device__ __forceinline__
void recur_chain8(const float* __restrict__ xp, const float* __restrict__ Whh,
                  const float* __restrict__ weff, float* __restrict__ partbuf,
                  int b, int blk, float (*hbuf)[192])
{
    const int tid = threadIdx.x;
    const int w   = tid >> 6;
    const int l   = tid & 63;
    const int g   = l & 15;
    const int m   = l >> 4;
    const int j0  = w * 32 + m * 8;
    const bool wr = (g == 15);

    // Whh rows j0..j0+7, cols 8g..8g+7  -> 64 regs
    float whh[64];
    #pragma unroll
    for (int jj = 0; jj < 8; ++jj)
        #pragma unroll
        for (int i = 0; i < 2; ++i)
            ((float4*)whh)[jj * 2 + i] =
                *(const float4*)(Whh + (j0 + jj) * H_SZ + g * 8 + i * 4);

    const float4 w4a = *(const float4*)(weff + DIR * H_SZ + j0);
    const float4 w4b = *(const float4*)(weff + DIR * H_SZ + j0 + 4);

    const float4* rd0 = (const float4*)&hbuf[0][12 * g];
    const float4* rd1 = (const float4*)&hbuf[1][12 * g];
    float* wp0 = &hbuf[0][12 * (4 * w + m)];
    float* wp1 = &hbuf[1][12 * (4 * w + m)];

    const float* xbase = xp + (size_t)(DIR * 64 + b) * T_LEN * H_SZ + j0;
    float* pst = partbuf + ((size_t)blk * 4 + w) * T_LEN + (DIR ? (T_LEN - 8) : 0);

    // two xp slots (distance-2 prefetch, refill-late)
    float4 Xs0a, Xs0b, Xs1a, Xs1b;
    {
        const int ta = DIR ? (T_LEN - 1) : 0;
        const int tb = DIR ? (T_LEN - 2) : 1;
        Xs0a = *(const float4*)(xbase + ((size_t)ta << 7));
        Xs0b = *(const float4*)(xbase + ((size_t)ta << 7) + 4);
        Xs1a = *(const float4*)(xbase + ((size_t)tb << 7));
        Xs1b = *(const float4*)(xbase + ((size_t)tb << 7) + 4);
    }

    float ps[8];

#define KSTEP(K) do {                                                          \
        /* 1. h read (2 x b128, 2-way-free banks) */                           \
        float4 hv0, hv1;                                                       \
        if ((K) & 1) { hv0 = rd1[0]; hv1 = rd1[1]; }                           \
        else         { hv0 = rd0[0]; hv1 = rd0[1]; }                           \
        /* 2. 64 FMA: 8 accs x (1 mul + 7 fma) */                              \
        float a0, a1, a2, a3, a4, a5, a6, a7;                                  \
        {                                                                      \
            const float* h_ = (const float*)&hv0;                              \
            a0 = whh[ 0] * h_[0]; a1 = whh[ 8] * h_[0];                        \
            a2 = whh[16] * h_[0]; a3 = whh[24] * h_[0];                        \
            a4 = whh[32] * h_[0]; a5 = whh[40] * h_[0];                        \
            a6 = whh[48] * h_[0]; a7 = whh[56] * h_[0];                        \
            _Pragma("unroll") for (int c = 1; c < 4; ++c) {                    \
                a0 = fmaf(whh[ 0 + c], h_[c], a0);                             \
                a1 = fmaf(whh[ 8 + c], h_[c], a1);                             \
                a2 = fmaf(whh[16 + c], h_[c], a2);                             \
                a3 = fmaf(whh[24 + c], h_[c], a3);                             \
                a4 = fmaf(whh[32 + c], h_[c], a4);                             \
                a5 = fmaf(whh[40 + c], h_[c], a5);                             \
                a6 = fmaf(whh[48 + c], h_[c], a6);                             \
                a7 = fmaf(whh[56 + c], h_[c], a7);                             \
            }                                                                  \
            const float* h2_ = (const float*)&hv1;                             \
            _Pragma("unroll") for (int c = 0; c < 4; ++c) {                    \
                a0 = fmaf(whh[ 4 + c], h2_[c], a0);                            \
                a1 = fmaf(whh[12 + c], h2_[c], a1);                            \
                a2 = fmaf(whh[20 + c], h2_[c], a2);                            \
                a3 = fmaf(whh[28 + c], h2_[c], a3);                            \
                a4 = fmaf(whh[36 + c], h2_[c], a4);                            \
                a5 = fmaf(whh[44 + c], h2_[c], a5);                            \
                a6 = fmaf(whh[52 + c], h2_[c], a6);                            \
                a7 = fmaf(whh[60 + c], h2_[c], a7);                            \
            }                                                                  \
        }                                                                      \
        /* 3. 4-level DPP reduce over the 16-lane row -> lane 15 */            \
        DPP_ADD_F32(a0, 0x111); DPP_ADD_F32(a1, 0x111);                        \
        DPP_ADD_F32(a2, 0x111); DPP_ADD_F32(a3, 0x111);                        \
        DPP_ADD_F32(a4, 0x111); DPP_ADD_F32(a5, 0x111);                        \
        DPP_ADD_F32(a6, 0x111); DPP_ADD_F32(a7, 0x111);                        \
        DPP_ADD_F32(a0, 0x112); DPP_ADD_F32(a1, 0x112);                        \
        DPP_ADD_F32(a2, 0x112); DPP_ADD_F32(a3, 0x112);                        \
        DPP_ADD_F32(a4, 0x112); DPP_ADD_F32(a5, 0x112);                        \
        DPP_ADD_F32(a6, 0x112); DPP_ADD_F32(a7, 0x112);                        \
        DPP_ADD_F32(a0, 0x114); DPP_ADD_F32(a1, 0x114);                        \
        DPP_ADD_F32(a2, 0x114); DPP_ADD_F32(a3, 0x114);                        \
        DPP_ADD_F32(a4, 0x114); DPP_ADD_F32(a5, 0x114);                        \
        DPP_ADD_F32(a6, 0x114); DPP_ADD_F32(a7, 0x114);                        \
        DPP_ADD_F32(a0, 0x118); DPP_ADD_F32(a1, 0x118);                        \
        DPP_ADD_F32(a2, 0x118); DPP_ADD_F32(a3, 0x118);                        \
        DPP_ADD_F32(a4, 0x118); DPP_ADD_F32(a5, 0x118);                        \
        DPP_ADD_F32(a6, 0x118); DPP_ADD_F32(a7, 0x118);                        \
        /* 4. writer: + xp, relu, h write, p dot */                            \
        float pv = 0.0f;                                                       \
        if (wr) {                                                              \
            float4 xa_ = ((K) & 1) ? Xs1a : Xs0a;                              \
            float4 xb_ = ((K) & 1) ? Xs1b : Xs0b;                              \
            float4 h4a, h4b;                                                   \
            h4a.x = fmaxf(a0 + xa_.x, 0.0f); h4a.y = fmaxf(a1 + xa_.y, 0.0f);  \
            h4a.z = fmaxf(a2 + xa_.z, 0.0f); h4a.w = fmaxf(a3 + xa_.w, 0.0f);  \
            h4b.x = fmaxf(a4 + xb_.x, 0.0f); h4b.y = fmaxf(a5 + xb_.y, 0.0f);  \
            h4b.z = fmaxf(a6 + xb_.z, 0.0f); h4b.w = fmaxf(a7 + xb_.w, 0.0f);  \
            float* wp_ = ((K) & 1) ? wp0 : wp1;                                \
            *(float4*)wp_ = h4a;                                               \
            *(float4*)(wp_ + 4) = h4b;                                         \
            pv = fmaf(w4a.x, h4a.x, fmaf(w4a.y, h4a.y,                         \
                 fmaf(w4a.z, h4a.z, fmaf(w4a.w, h4a.w,                         \
                 fmaf(w4b.x, h4b.x, fmaf(w4b.y, h4b.y,                         \
                 fmaf(w4b.z, h4b.z, w4b.w * h4b.w)))))));                      \
        }                                                                      \
        /* 5. refill-late: xp for step s+2 (clamped) */                        \
        {                                                                      \
            int tp = sbase + (K) + 2;                                          \
            tp = (tp < T_LEN) ? tp : (T_LEN - 1);                              \
            const int tl = DIR ? (T_LEN - 1 - tp) : tp;                        \
            const float* xr_ = xbase + ((size_t)tl << 7);                      \
            if ((K) & 1) { Xs1a = *(const float4*)xr_;                         \
                           Xs1b = *(const float4*)(xr_ + 4); }                 \
            else         { Xs0a = *(const float4*)xr_;                         \
                           Xs0b = *(const float4*)(xr_ + 4); }                 \
        }                                                                      \
        /* 6. p-reduce: writers at 15/31/47/63 -> lane 63 */                   \
        DPP_ADD_F32(pv, 0x142);  /* row_bcast:15 */                            \
        DPP_ADD_F32(pv, 0x143);  /* row_bcast:31 */                            \
        ps[K] = pv;                                                            \
        chain_barrier();                                                       \
    } while (0)

    #pragma unroll 1
    for (int it = 0; it < T_LEN / 8; ++it) {
        const int sbase = it * 8;
        KSTEP(0); KSTEP(1); KSTEP(2); KSTEP(3);
        KSTEP(4); KSTEP(5); KSTEP(6); KSTEP(7);
        if (l == 63) {
            float4 v0, v1;
            if (DIR) { v0 = make_float4(ps[7], ps[6], ps[5], ps[4]);
                       v1 = make_float4(ps[3], ps[2], ps[1], ps[0]); }
            else     { v0 = make_float4(ps[0], ps[1], ps[2], ps[3]);
                       v1 = make_float4(ps[4], ps[5], ps[6], ps[7]); }
            *(float4*)pst = v0; *(float4*)(pst + 4) = v1;
        }
        pst += DIR ? -8 : 8;
    }
#undef KSTEP
}

__global__ __launch_bounds__(256, 1)
void brnn_recur_xp8(const float* __restrict__ xp,
                    const float* __restrict__ Whh_f, const float* __restrict__ Whh_b,
                    const float* __restrict__ weff,  float* __restrict__ partbuf)
{
    __shared__ __align__(16) float hbuf[2][192];
    const int blk = blockIdx.x;
    const int dir = blk >> 6;
    const int b   = blk & 63;
    if (threadIdx.x < 192) hbuf[0][threadIdx.x] = 0.0f;
    __syncthreads();
    if (dir == 0) recur_chain8<0>(xp, Whh_f, weff, partbuf, b, blk, hbuf);
    else          recur_chain8<1>(xp, Whh_b, weff, partbuf, b, blk, hbuf);
}

// ---------------------------------------------------------------------------
// Fallback recurrence (round-4 structure, x in-loop) for small ws_size.
// ---------------------------------------------------------------------------
__global__ __launch_bounds__(256, 1)
void brnn_recur_fb(const float* __restrict__ x,
                   const float* __restrict__ Wih_f, const float* __restrict__ Whh_f,
                   const float* __restrict__ bih_f, const float* __restrict__ bhh_f,
                   const float* __restrict__ Wih_b, const float* __restrict__ Whh_b,
                   const float* __restrict__ bih_b, const float* __restrict__ bhh_b,
                   const float* __restrict__ weff,  float* __restrict__ partbuf)
{
    const int blk  = blockIdx.x;
    const int dir  = blk >> 6;
    const int b    = blk & 63;
    const int tid  = threadIdx.x;
    const int w    = tid >> 6;
    const int l    = tid & 63;
    const int g    = l & 7;
    const int m    = l >> 3;
    const int j0   = w * 32 + m * 4;
    const bool wr  = (g == 7);

    const float* Wih = dir ? Wih_b : Wih_f;
    const float* Whh = dir ? Whh_b : Whh_f;
    const float* bih = dir ? bih_b : bih_f;
    const float* bhh = dir ? bhh_b : bhh_f;

    float whh[64];
    #pragma unroll
    for (int jj = 0; jj < 4; ++jj)
        #pragma unroll
        for (int i = 0; i < 4; ++i)
            ((float4*)whh)[jj * 4 + i] =
                *(const float4*)(Whh + (j0 + jj) * 128 + g * 16 + i * 4);
    float wih[32];
    #pragma unroll
    for (int jj = 0; jj < 4; ++jj)
        #pragma unroll
        for (int i = 0; i < 2; ++i)
            ((float4*)wih)[jj * 2 + i] =
                *(const float4*)(Wih + (j0 + jj) * 64 + g * 8 + i * 4);

    float4 b4 = make_float4(0.f, 0.f, 0.f, 0.f);
    if (g == 0) {
        float4 bi = *(const float4*)(bih + j0);
        float4 bh = *(const float4*)(bhh + j0);
        b4 = make_float4(bi.x + bh.x, bi.y + bh.y, bi.z + bh.z, bi.w + bh.w);
    }
    const float4 w4 = *(const float4*)(weff + dir * 128 + j0);

    __shared__ __align__(16) float hbuf[2][160];
    if (tid < 160) hbuf[0][tid] = 0.0f;
    __syncthreads();

    const float* xbase = x + (size_t)b * T_LEN * D_IN + g * 8;
    float* pout = partbuf + ((size_t)blk * 4 + w) * T_LEN;

    float xq0[8], xq1[8], xq2[8], xq3[8];
    {
        const float4* xp0 = (const float4*)(xbase + (size_t)(dir ? (T_LEN - 1) : 0) * D_IN);
        ((float4*)xq0)[0] = xp0[0];
        ((float4*)xq0)[1] = xp0[1];
        const float4* xp1 = (const float4*)(xbase + (size_t)(dir ? (T_LEN - 2) : 1) * D_IN);
        ((float4*)xq1)[0] = xp1[0];
        ((float4*)xq1)[1] = xp1[1];
    }

    float p_carry = 0.0f;
    int   t_prev  = 0;
    const int hwidx = 40 * w + 4 * m + 4 * (m >> 2);

#define STEP(S, RD, XCUR, XPRE) do {                                           \
        const int s_  = (S);                                                   \
        if (s_ > 0) {                                                          \
            float pr_ = p_carry;                                               \
            DPP_ADD_F32(pr_, 0x118); DPP_ADD_F32(pr_, 0x142);                  \
            DPP_ADD_F32(pr_, 0x143);                                           \
            if (l == 63) pout[t_prev] = pr_;                                   \
        }                                                                      \
        {                                                                      \
            const int sp_ = (s_ + 2 < T_LEN) ? (s_ + 2) : (T_LEN - 1);         \
            const int tp_ = dir ? (T_LEN - 1 - sp_) : sp_;                     \
            const float4* xp_ = (const float4*)(xbase + (size_t)tp_ * D_IN);   \
            ((float4*)XPRE)[0] = xp_[0];                                       \
            ((float4*)XPRE)[1] = xp_[1];                                       \
        }                                                                      \
        const float4* hp_ = (const float4*)&hbuf[RD][20 * g];                  \
        float4 hv_[4];                                                         \
        _Pragma("unroll") for (int i = 0; i < 4; ++i) hv_[i] = hp_[i];         \
        float a0 = b4.x, a1 = b4.y, a2 = b4.z, a3 = b4.w;                      \
        _Pragma("unroll") for (int i = 0; i < 8; ++i) {                        \
            a0 = fmaf(wih[0 * 8 + i], XCUR[i], a0);                            \
            a1 = fmaf(wih[1 * 8 + i], XCUR[i], a1);                            \
            a2 = fmaf(wih[2 * 8 + i], XCUR[i], a2);                            \
            a3 = fmaf(wih[3 * 8 + i], XCUR[i], a3);                            \
        }                                                                      \
        _Pragma("unroll") for (int i = 0; i < 4; ++i) {                        \
            const float* hq_ = (const float*)&hv_[i];                          \
            _Pragma("unroll") for (int c = 0; c < 4; ++c) {                    \
                a0 = fmaf(whh[0 * 16 + i * 4 + c], hq_[c], a0);                \
                a1 = fmaf(whh[1 * 16 + i * 4 + c], hq_[c], a1);                \
                a2 = fmaf(whh[2 * 16 + i * 4 + c], hq_[c], a2);                \
                a3 = fmaf(whh[3 * 16 + i * 4 + c], hq_[c], a3);                \
            }                                                                  \
        }                                                                      \
        DPP_ADD_F32(a0, 0x111); DPP_ADD_F32(a1, 0x111);                        \
        DPP_ADD_F32(a2, 0x111); DPP_ADD_F32(a3, 0x111);                        \
        DPP_ADD_F32(a0, 0x112); DPP_ADD_F32(a1, 0x112);                        \
        DPP_ADD_F32(a2, 0x112); DPP_ADD_F32(a3, 0x112);                        \
        DPP_ADD_F32(a0, 0x114); DPP_ADD_F32(a1, 0x114);                        \
        DPP_ADD_F32(a2, 0x114); DPP_ADD_F32(a3, 0x114);                        \
        float4 h4_;                                                            \
        h4_.x = fmaxf(a0, 0.0f); h4_.y = fmaxf(a1, 0.0f);                      \
        h4_.z = fmaxf(a2, 0.0f); h4_.w = fmaxf(a3, 0.0f);                      \
        p_carry = 0.0f;                                                        \
        if (wr) {                                                              \
            *(float4*)&hbuf[(RD) ^ 1][hwidx] = h4_;                            \
            p_carry = w4.x * h4_.x + w4.y * h4_.y                              \
                    + w4.z * h4_.z + w4.w * h4_.w;                             \
        }                                                                      \
        t_prev = dir ? (T_LEN - 1 - s_) : s_;                                  \
        chain_barrier_strict();                                                \
    } while (0)

    #pragma unroll 1
    for (int s = 0; s < T_LEN; s += 4) {
        STEP(s,     0, xq0, xq2);
        STEP(s + 1, 1, xq1, xq3);
        STEP(s + 2, 0, xq2, xq0);
        STEP(s + 3, 1, xq3, xq1);
    }
#undef STEP

    {
        float pr = p_carry;
        DPP_ADD_F32(pr, 0x118); DPP_ADD_F32(pr, 0x142); DPP_ADD_F32(pr, 0x143);
        if (l == 63) pout[t_prev] = pr;
    }
}

// ---------------------------------------------------------------------------
// Kernel 3: assemble logits from partials and log-softmax over T per batch.
// ---------------------------------------------------------------------------
__global__ __launch_bounds__(256)
void brnn_lsm(const float* __restrict__ partbuf, const float* __restrict__ ws,
              float* __restrict__ out)
{
    const int b   = blockIdx.x;
    const int tid = threadIdx.x;
    __shared__ float lg[T_LEN];
    __shared__ float red[8];

    const float beff = ws[256];

    float lmax = -3.0e38f;
    for (int t = tid; t < T_LEN; t += 256) {
        float s = beff;
        #pragma unroll
        for (int dw = 0; dw < 8; ++dw) {
            const int dir = dw >> 2, wv = dw & 3;
            s += partbuf[(((size_t)(dir * 64 + b)) * 4 + wv) * T_LEN + t];
        }
        lg[t] = s;
        lmax = fmaxf(lmax, s);
    }
    #pragma unroll
    for (int mm = 1; mm <= 32; mm <<= 1) lmax = fmaxf(lmax, __shfl_xor(lmax, mm));
    if ((tid & 63) == 0) red[tid >> 6] = lmax;
    __syncthreads();
    const float bmax = fmaxf(fmaxf(red[0], red[1]), fmaxf(red[2], red[3]));

    float lsum = 0.0f;
    for (int t = tid; t < T_LEN; t += 256) lsum += expf(lg[t] - bmax);
    #pragma unroll
    for (int mm = 1; mm <= 32; mm <<= 1) lsum += __shfl_xor(lsum, mm);
    if ((tid & 63) == 0) red[4 + (tid >> 6)] = lsum;
    __syncthreads();
    const float lse = bmax + logf(red[4] + red[5] + red[6] + red[7]);

    for (int t = tid; t < T_LEN; t += 256)
        out[(size_t)b * T_LEN + t] = lg[t] - lse;
}

// ---------------------------------------------------------------------------
extern "C" void kernel_launch(void* const* d_in, const int* in_sizes, int n_in,
                              void* d_out, int out_size, void* d_ws, size_t ws_size,
                              hipStream_t stream)
{
    const float* x     = (const float*)d_in[0];
    const float* Wih_f = (const float*)d_in[1];
    const float* Whh_f = (const float*)d_in[2];
    const float* bih_f = (const float*)d_in[3];
    const float* bhh_f = (const float*)d_in[4];
    const float* Wih_b = (const float*)d_in[5];
    const float* Whh_b = (const float*)d_in[6];
    const float* bih_b = (const float*)d_in[7];
    const float* bhh_b = (const float*)d_in[8];
    const float* fc1_W = (const float*)d_in[9];
    const float* fc1_b = (const float*)d_in[10];
    const float* fc2_W = (const float*)d_in[11];
    const float* fc2_b = (const float*)d_in[12];
    float* out = (float*)d_out;

    float* wsf = (float*)d_ws;
    const size_t part_off   = 512;
    const size_t part_elems = (size_t)2 * 64 * 4 * T_LEN;          // 1 Mi floats
    const size_t xp_off     = part_off + part_elems;
    const size_t xp_elems   = (size_t)2 * 64 * T_LEN * H_SZ;       // 32 Mi floats
    float* part = wsf + part_off;
    float* xpbf = wsf + xp_off;
    const bool big_ws = ws_size >= (xp_off + xp_elems) * sizeof(float);

    hipLaunchKernelGGL(prep_kernel, dim3(1), dim3(256), 0, stream,
                       fc1_W, fc1_b, fc2_W, fc2_b, wsf);
    if (big_ws) {
        hipLaunchKernelGGL(xp_gemm, dim3(4096), dim3(256), 0, stream,
                           x, Wih_f, bih_f, bhh_f, Wih_b, bih_b, bhh_b, xpbf);
        hipLaunchKernelGGL(brnn_recur_xp8, dim3(128), dim3(256), 0, stream,
                           xpbf, Whh_f, Whh_b, wsf, part);
    } else {
        hipLaunchKernelGGL(brnn_recur_fb, dim3(128), dim3(256), 0, stream,
                           x, Wih_f, Whh_f, bih_f, bhh_f,
                           Wih_b, Whh_b, bih_b, bhh_b, wsf, part);
    }
    hipLaunchKernelGGL(brnn_lsm, dim3(64), dim3(256), 0, stream,
                       part, wsf, out);
}